// Round 6
// baseline (20.771 us; speedup 1.0000x reference)
//
#include <hip/hip_runtime.h>

// Rank IGR Loss — ONE kernel, fence-free cross-block tail.
//
// R4 lesson: per-block __threadfence (L2 writeback-inv on gfx9) x1024 cost
// ~20us. Atomics alone are device-coherent (cross-XCD) on CDNA4, so the tail
// here uses ONLY atomics: publish partials via atomicExch (u64, distinct
// slots), order via consumed return values (vmcnt ack), elect last block via
// atomicAdd on a __device__ counter, read back via atomicOr(.,0). Counter is
// self-resetting (last block zeroes it) -> survives ws poisoning, no memset
// node, deterministic (no accumulation atomics; fixed reduce order).
//
// Math (validated absmax 0.0 in R3-R5): per-block sorted 64-elem j-tile by
// d' = pos ? d : -1e30 (ties by index), inclusive suffix sums of
// w1=e^{G1 p}, w2=e^{G2 iou}; per i a 6-probe lower_bound with the EXACT
// brute-force f32 predicate (d_j - d_i >= 1.0f, monotone in d_j) + one
// suffix lookup. Non-pos j sort to the front, never reached; non-pos i have
// v1=v2=0.

#define G1 3.0f
#define G2 1.0f

constexpr int B    = 16;
constexpr int N    = 2048;
constexpr int TJ   = 64;          // sorted j-tile per block
constexpr int IPT  = 8;           // i per thread (full N i-strip per block)
constexpr int JCH  = N / TJ;      // 32
constexpr int NBLK = B * JCH;     // 512

__device__ unsigned g_cnt;        // 0 at load; every run leaves it 0

__global__ void __launch_bounds__(256)
igr_kernel(const float* __restrict__ cls, const int* __restrict__ label_cls,
           const float* __restrict__ label_loc, const float* __restrict__ pred,
           const float* __restrict__ tgt, const int* __restrict__ dataset_id,
           double* __restrict__ part, float* __restrict__ out) {
  __shared__ uint4  stile[TJ];            // {ordkey(d'), idx, w1 bits, w2 bits}
  __shared__ float  ssd[TJ];
  __shared__ float  suf1[TJ + 1], suf2[TJ + 1];
  __shared__ double red[3][4];
  __shared__ double bl1[B], bl2[B], bval[B];
  __shared__ unsigned s_last;

  const int bid  = blockIdx.x;
  const int b    = bid >> 5;              // / JCH
  const int jc   = bid & 31;
  const int t    = threadIdx.x;
  const int base = b * N;

  const float tx1 = tgt[b * 4 + 0], ty1 = tgt[b * 4 + 1];
  const float tx2 = tgt[b * 4 + 2], ty2 = tgt[b * 4 + 3];
  const float ta  = (tx2 - tx1) * (ty2 - ty1);
  const float tcx = (tx1 + tx2) * 0.5f, tcy = (ty1 + ty2) * 0.5f;

  const float* __restrict__ pb = pred      + (size_t)b * 4 * N;
  const float* __restrict__ lb = label_loc + (size_t)b * 4 * N;

  auto elem = [&](int n, float& d, float& prob, float& iou, bool& pos) {
    float x1 = pb[n], y1 = pb[N + n], x2 = pb[2 * N + n], y2 = pb[3 * N + n];
    float ww = fmaxf(fminf(tx2, x2) - fmaxf(tx1, x1), 0.f);
    float hh = fmaxf(fminf(ty2, y2) - fmaxf(ty1, y1), 0.f);
    float inter = ww * hh;
    iou  = inter / ((x2 - x1) * (y2 - y1) + ta - inter);
    prob = __expf(cls[((size_t)(base + n)) * 2 + 1]);
    pos  = label_cls[base + n] > 0;
    float cx = lb[n] + tx1, cy = lb[N + n] + ty1;
    float dx = cx - tcx, dy = cy - tcy;
    d = sqrtf(dx * dx + dy * dy);
  };

  // ---- stage j tile (wave 0) ----
  float dm_j = 0.f; unsigned uj = 0u;
  if (t < TJ) {
    float d, prob, iou; bool pos;
    elem(jc * TJ + t, d, prob, iou, pos);
    dm_j = pos ? d : -1e30f;
    uj = __float_as_uint(dm_j);
    uj ^= (uj & 0x80000000u) ? 0xFFFFFFFFu : 0x80000000u;   // order-preserving
    stile[t] = make_uint4(uj, (unsigned)t,
                          __float_as_uint(__expf(G1 * prob)),
                          __float_as_uint(__expf(G2 * iou)));
  }
  if (t == TJ) { suf1[TJ] = 0.f; suf2[TJ] = 0.f; }

  // ---- per-thread i data (8 coalesced strips covering all of N) ----
  float di[IPT], v1i[IPT], v2i[IPT];
#pragma unroll
  for (int k = 0; k < IPT; ++k) {
    float d, prob, iou; bool pos;
    elem(k * 256 + t, d, prob, iou, pos);
    di[k]  = d;
    v1i[k] = pos ? __expf(-G1 * prob) : 0.f;   // >0 iff pos
    v2i[k] = pos ? __expf(-G2 * iou)  : 0.f;
  }
  __syncthreads();

  // ---- rank-sort + inclusive suffix sums (wave 0) ----
  if (t < TJ) {
    const unsigned long long mykey = ((unsigned long long)uj << 32) | (unsigned)t;
    int rank = 0; float s1 = 0.f, s2 = 0.f;
#pragma unroll 8
    for (int q = 0; q < TJ; ++q) {
      uint4 v = stile[q];                      // LDS broadcast
      unsigned long long kq = ((unsigned long long)v.x << 32) | v.y;
      bool lt = kq < mykey;
      rank += lt ? 1 : 0;
      s1 += lt ? 0.f : __uint_as_float(v.z);
      s2 += lt ? 0.f : __uint_as_float(v.w);
    }
    ssd[rank] = dm_j; suf1[rank] = s1; suf2[rank] = s2;    // bijective fill
  }
  __syncthreads();

  // ---- 8 binary searches + suffix lookups ----
  double p1 = 0.0, p2 = 0.0; int cnt = 0;
#pragma unroll
  for (int k = 0; k < IPT; ++k) {
    const float d = di[k];
    int kk = 0;
#pragma unroll
    for (int w = TJ >> 1; w > 0; w >>= 1)      // exact monotone f32 predicate
      kk += (ssd[kk + w - 1] - d >= 1.0f) ? 0 : w;
    kk += (ssd[kk] - d >= 1.0f) ? 0 : 1;       // kk in [0, TJ]
    p1 += (double)v1i[k] * (double)suf1[kk];
    p2 += (double)v2i[k] * (double)suf2[kk];
    cnt += (v1i[k] > 0.f) ? (TJ - kk) : 0;
  }
  double pc = (double)cnt;

  for (int off = 32; off; off >>= 1) {
    p1 += __shfl_down(p1, off);
    p2 += __shfl_down(p2, off);
    pc += __shfl_down(pc, off);
  }
  const int wv = t >> 6, lane = t & 63;
  if (lane == 0) { red[0][wv] = p1; red[1][wv] = p2; red[2][wv] = pc; }
  __syncthreads();

  // ---- publish partials (atomicExch = device-coherent, no fence) + elect ----
  if (t == 0) {
    double a = red[0][0] + red[0][1] + red[0][2] + red[0][3];
    double c = red[1][0] + red[1][1] + red[1][2] + red[1][3];
    double e = red[2][0] + red[2][1] + red[2][2] + red[2][3];
    unsigned long long* pp = (unsigned long long*)(part + (size_t)bid * 3);
    unsigned long long o0 = atomicExch(pp + 0, __double_as_longlong(a));
    unsigned long long o1 = atomicExch(pp + 1, __double_as_longlong(c));
    unsigned long long o2 = atomicExch(pp + 2, __double_as_longlong(e));
    // consume returns -> s_waitcnt vmcnt: exchanges acked at LLC before elect
    asm volatile("" :: "v"(o0), "v"(o1), "v"(o2));
    unsigned old = atomicAdd(&g_cnt, 1u);
    s_last = (old == (unsigned)(NBLK - 1)) ? 1u : 0u;
  }
  __syncthreads();

  if (s_last) {                                // uniform branch (shared flag)
    const int tb = t >> 4, kq = t & 15;        // 16 batches x 16 threads
    double q1 = 0, q2 = 0, qc = 0;
#pragma unroll
    for (int h = 0; h < 2; ++h) {              // 32 partials per batch
      size_t p = (size_t)(tb * JCH + kq + h * 16) * 3;
      unsigned long long* pp = (unsigned long long*)part;
      q1 += __longlong_as_double(atomicOr(pp + p + 0, 0ull));  // coherent read
      q2 += __longlong_as_double(atomicOr(pp + p + 1, 0ull));
      qc += __longlong_as_double(atomicOr(pp + p + 2, 0ull));
    }
    for (int off = 8; off; off >>= 1) {
      q1 += __shfl_down(q1, off, 16);
      q2 += __shfl_down(q2, off, 16);
      qc += __shfl_down(qc, off, 16);
    }
    if (kq == 0) {
      bool valid = (dataset_id[tb] != 1) && (qc > 0.0);
      double denom = fmax(qc, 1.0);
      bl1[tb]  = valid ? q1 / denom : 0.0;
      bl2[tb]  = valid ? q2 / denom : 0.0;
      bval[tb] = valid ? 1.0 : 0.0;
    }
    __syncthreads();
    if (t == 0) {
      double nv = 0, f1 = 0, f2 = 0;
      for (int x = 0; x < B; ++x) { nv += bval[x]; f1 += bl1[x]; f2 += bl2[x]; }
      out[0] = (float)((nv > 0) ? f1 / nv : 0.0);
      out[1] = (float)((nv > 0) ? f2 / nv : 0.0);
      atomicExch(&g_cnt, 0u);                  // self-reset for next run
    }
  }
}

extern "C" void kernel_launch(void* const* d_in, const int* in_sizes, int n_in,
                              void* d_out, int out_size, void* d_ws, size_t ws_size,
                              hipStream_t stream) {
  const float* cls       = (const float*)d_in[0];
  const int*   label_cls = (const int*)d_in[1];
  const float* label_loc = (const float*)d_in[2];
  const float* pred      = (const float*)d_in[3];
  const float* tgt       = (const float*)d_in[4];
  const int*   dset      = (const int*)d_in[5];

  double* part = (double*)d_ws;   // NBLK*3 doubles = 12 KB (all slots written
                                  // each run before any read -> poison-safe)

  igr_kernel<<<NBLK, 256, 0, stream>>>(cls, label_cls, label_loc, pred, tgt,
                                       dset, part, (float*)d_out);
}